// Round 1
// baseline (326.350 us; speedup 1.0000x reference)
//
#include <hip/hip_runtime.h>
#include <hip/hip_bf16.h>
#include <stdint.h>

typedef __bf16 bf16;
typedef __attribute__((ext_vector_type(4))) float f32x4;
typedef __attribute__((ext_vector_type(8))) bf16 bf16x8;
typedef __attribute__((ext_vector_type(4))) bf16 bf16x4;

#define AS1 __attribute__((address_space(1)))
#define AS3 __attribute__((address_space(3)))

static __device__ __forceinline__ void gload_lds16(const bf16* g, bf16* l) {
  __builtin_amdgcn_global_load_lds((const AS1 void*)g, (AS3 void*)l, 16, 0, 0);
}

// ---------------- prep: roll + reorder + fp32->bf16 ----------------
// xs rows are ordered m = ((b*64 + win)*64 + t); xs[m][c] = x[b][(i'+4)%64][(j'+4)%64][c]
__global__ __launch_bounds__(256) void prep_x(const float* __restrict__ x,
                                              bf16* __restrict__ xs) {
  int m = blockIdx.x * 8 + (threadIdx.x >> 5);
  int lane = threadIdx.x & 31;
  int b = m >> 12, win = (m >> 6) & 63, t = m & 63;
  int ip = ((win >> 3) << 3) + (t >> 3);
  int jp = ((win & 7) << 3) + (t & 7);
  int io = (ip + 4) & 63, jo = (jp + 4) & 63;
  const float* src = x + ((((size_t)(b << 6) + io) << 6) + jo) * 512;
  bf16* dst = xs + ((size_t)m << 9);
  #pragma unroll
  for (int c0 = 0; c0 < 512; c0 += 128) {
    int c = c0 + lane * 4;
    float4 v = *(const float4*)(src + c);
    bf16x4 o = { (bf16)v.x, (bf16)v.y, (bf16)v.z, (bf16)v.w };
    *(bf16x4*)(dst + c) = o;
  }
}

// w_qkv rows [0,512) are the q-projection: fold softmax scale 1/sqrt(32) there.
__global__ __launch_bounds__(256) void prep_w(const float* __restrict__ wqkv,
                                              const float* __restrict__ wout,
                                              bf16* __restrict__ wqkv_bf,
                                              bf16* __restrict__ wout_bf) {
  int r = blockIdx.x * 8 + (threadIdx.x >> 5);
  int lane = threadIdx.x & 31;
  const float* src;
  bf16* dst;
  float sc = 1.0f;
  if (r < 1536) {
    src = wqkv + (size_t)r * 512;
    dst = wqkv_bf + (size_t)r * 512;
    if (r < 512) sc = 0.17677669529663689f;
  } else {
    int r2 = r - 1536;
    src = wout + (size_t)r2 * 512;
    dst = wout_bf + (size_t)r2 * 512;
  }
  #pragma unroll
  for (int c0 = 0; c0 < 512; c0 += 128) {
    int c = c0 + lane * 4;
    float4 v = *(const float4*)(src + c);
    bf16x4 o = { (bf16)(v.x * sc), (bf16)(v.y * sc), (bf16)(v.z * sc), (bf16)(v.w * sc) };
    *(bf16x4*)(dst + c) = o;
  }
}

// 4 bias tables: type = (UL?1:0) | (LR?2:0).
// bias[i][j] = pos[(j>>3)-(i>>3)+7][(j&7)-(i&7)+7]  (rel = coords[j]-coords[i])
__global__ __launch_bounds__(256) void prep_bias(const float* __restrict__ pos,
                                                 float* __restrict__ bias4) {
  for (int idx = threadIdx.x; idx < 4 * 4096; idx += 256) {
    int ty = idx >> 12, ij = idx & 4095;
    int i = ij >> 6, j = ij & 63;
    int rx = ((j >> 3) - (i >> 3)) + 7;
    int ry = ((j & 7) - (i & 7)) + 7;
    float v = pos[rx * 15 + ry];
    if ((ty & 1) && (((i ^ j) >> 5) & 1)) v = -1e30f;  // upper/lower mask
    if ((ty & 2) && (((i ^ j) >> 2) & 1)) v = -1e30f;  // left/right mask
    bias4[idx] = v;
  }
}

// ---------------- QKV GEMM: [65536,512] x [1536,512]^T ----------------
// BM=BN=128, BK=32; 4 waves 2x2; m97 structure (global_load_lds w=16, 2 barriers/K-step).
// Epilogue: restage C in LDS (XOR-swizzled) -> contiguous 4KB chunks per (h,win):
//   q,k as [t][d]; v transposed as [d][t].
__global__ __launch_bounds__(256, 2) void gemm_qkv(
    const bf16* __restrict__ xs, const bf16* __restrict__ wb,
    bf16* __restrict__ qb, bf16* __restrict__ kb, bf16* __restrict__ vb) {
  __shared__ union {
    struct { bf16 A[128][32]; bf16 B[128][32]; } s;
    bf16 C[128][128];
  } sm;
  const int tid = threadIdx.x, wave = tid >> 6, lane = tid & 63;
  const int bid = blockIdx.x;
  const int mt = bid / 12, nt = bid % 12;

  const bf16* Ag = xs + ((size_t)mt * 128) * 512;
  const bf16* Bg = wb + ((size_t)nt * 128) * 512;
  const int srow = (wave << 5) + (lane >> 2);
  const int scol = (lane & 3) << 3;
  const bf16* ga = Ag + (size_t)srow * 512 + scol;
  const bf16* gb = Bg + (size_t)srow * 512 + scol;
  bf16* ldsA = &sm.s.A[wave << 5][0];
  bf16* ldsB = &sm.s.B[wave << 5][0];

  const int wr = (wave >> 1) << 6, wc = (wave & 1) << 6;
  const int lr = lane & 15, lg = lane >> 4;

  f32x4 acc[4][4] = {};

  for (int kt = 0; kt < 16; ++kt) {
    __syncthreads();
    gload_lds16(ga + kt * 32, ldsA);
    gload_lds16(ga + kt * 32 + 16 * 512, ldsA + 512);
    gload_lds16(gb + kt * 32, ldsB);
    gload_lds16(gb + kt * 32 + 16 * 512, ldsB + 512);
    __syncthreads();
    bf16x8 af[4], bfr[4];
    #pragma unroll
    for (int i = 0; i < 4; ++i) {
      af[i]  = *(const bf16x8*)&sm.s.A[wr + i * 16 + lr][lg << 3];
      bfr[i] = *(const bf16x8*)&sm.s.B[wc + i * 16 + lr][lg << 3];
    }
    #pragma unroll
    for (int i = 0; i < 4; ++i)
      #pragma unroll
      for (int j = 0; j < 4; ++j)
        acc[i][j] = __builtin_amdgcn_mfma_f32_16x16x32_bf16(af[i], bfr[j], acc[i][j], 0, 0, 0);
  }
  __syncthreads();
  // acc -> swizzled bf16 C tile in LDS
  #pragma unroll
  for (int i = 0; i < 4; ++i)
    #pragma unroll
    for (int j = 0; j < 4; ++j)
      #pragma unroll
      for (int r = 0; r < 4; ++r) {
        int row = wr + i * 16 + (lg << 2) + r;
        int col = wc + j * 16 + lr;
        sm.C[row][col ^ ((row & 7) << 3)] = (bf16)acc[i][j][r];
      }
  __syncthreads();
  const int sel = nt >> 2;
  #pragma unroll
  for (int ch = 0; ch < 2; ++ch) {
    int c = wave * 2 + ch;
    int wl = c >> 2, hl = c & 3;           // window-in-tile, head-in-tile
    int gw = mt * 2 + wl;                  // global window id
    int b = gw >> 6, win = gw & 63;
    int h = ((nt & 3) << 2) + hl;
    size_t ubase = ((size_t)((b << 4) + h) * 64 + win) * 2048;
    if (sel < 2) {
      bf16* dst = (sel == 0 ? qb : kb) + ubase;
      #pragma unroll
      for (int p = 0; p < 4; ++p) {
        int off = p * 512 + lane * 8;
        int t = off >> 5, d = off & 31;
        int row = (wl << 6) + t, col = (hl << 5) + d;
        bf16x8 v = *(const bf16x8*)&sm.C[row][col ^ ((row & 7) << 3)];
        *(bf16x8*)(dst + off) = v;         // q/k: [t][d] contiguous
      }
    } else {
      bf16* dst = vb + ubase;
      #pragma unroll
      for (int p = 0; p < 4; ++p) {
        int off = p * 512 + lane * 8;
        int d = off >> 6, t0 = off & 63;
        int col = (hl << 5) + d;
        bf16x8 v;
        #pragma unroll
        for (int q = 0; q < 8; ++q) {
          int row = (wl << 6) + t0 + q;
          v[q] = sm.C[row][col ^ ((row & 7) << 3)];
        }
        *(bf16x8*)(dst + off) = v;         // v: [d][t] contiguous (transposed)
      }
    }
  }
}

// ---------------- window attention: 1 wave per (b,h,win) ----------------
__global__ __launch_bounds__(256) void attn(
    const bf16* __restrict__ qb, const bf16* __restrict__ kb,
    const bf16* __restrict__ vb, const float* __restrict__ bias4,
    bf16* __restrict__ ao) {
  __shared__ bf16 Ps[4][64][72];
  const int wave = threadIdx.x >> 6, lane = threadIdx.x & 63;
  const int u = blockIdx.x * 4 + wave;
  const int b = u >> 10, h = (u >> 6) & 15, win = u & 63;
  const int lr = lane & 15, lg = lane >> 4;

  const bf16* qu = qb + (size_t)u * 2048;
  const bf16* ku = kb + (size_t)u * 2048;
  const bf16* vu = vb + (size_t)u * 2048;

  bf16x8 qf[4], kf[4];
  #pragma unroll
  for (int i = 0; i < 4; ++i) {
    qf[i] = *(const bf16x8*)(qu + (i * 16 + lr) * 32 + (lg << 3));
    kf[i] = *(const bf16x8*)(ku + (i * 16 + lr) * 32 + (lg << 3));
  }
  f32x4 s[4][4] = {};
  #pragma unroll
  for (int i = 0; i < 4; ++i)
    #pragma unroll
    for (int j = 0; j < 4; ++j)
      s[i][j] = __builtin_amdgcn_mfma_f32_16x16x32_bf16(qf[i], kf[j], s[i][j], 0, 0, 0);

  const int ty = ((win >= 56) ? 1 : 0) | (((win & 7) == 7) ? 2 : 0);
  const float* bt = bias4 + ty * 4096;
  #pragma unroll
  for (int i = 0; i < 4; ++i)
    #pragma unroll
    for (int r = 0; r < 4; ++r) {
      int row = i * 16 + (lg << 2) + r;
      #pragma unroll
      for (int j = 0; j < 4; ++j)
        s[i][j][r] += bt[row * 64 + j * 16 + lr];
    }
  // wave-parallel softmax: each row lives in 16 lanes (same lg), 4 cols each
  #pragma unroll
  for (int i = 0; i < 4; ++i)
    #pragma unroll
    for (int r = 0; r < 4; ++r) {
      float mx = fmaxf(fmaxf(s[i][0][r], s[i][1][r]), fmaxf(s[i][2][r], s[i][3][r]));
      mx = fmaxf(mx, __shfl_xor(mx, 1));
      mx = fmaxf(mx, __shfl_xor(mx, 2));
      mx = fmaxf(mx, __shfl_xor(mx, 4));
      mx = fmaxf(mx, __shfl_xor(mx, 8));
      float sum = 0.f;
      #pragma unroll
      for (int j = 0; j < 4; ++j) { s[i][j][r] = __expf(s[i][j][r] - mx); sum += s[i][j][r]; }
      sum += __shfl_xor(sum, 1);
      sum += __shfl_xor(sum, 2);
      sum += __shfl_xor(sum, 4);
      sum += __shfl_xor(sum, 8);
      float inv = 1.0f / sum;
      int row = i * 16 + (lg << 2) + r;
      #pragma unroll
      for (int j = 0; j < 4; ++j)
        Ps[wave][row][j * 16 + lr] = (bf16)(s[i][j][r] * inv);
    }
  // PV: out[64x32] = P[64x64] @ v ; B^T = vT[d][t] is K-contiguous
  f32x4 o[4][2] = {};
  #pragma unroll
  for (int kk = 0; kk < 2; ++kk) {
    bf16x8 vf[2];
    #pragma unroll
    for (int nj = 0; nj < 2; ++nj)
      vf[nj] = *(const bf16x8*)(vu + (nj * 16 + lr) * 64 + kk * 32 + (lg << 3));
    #pragma unroll
    for (int mi = 0; mi < 4; ++mi) {
      bf16x8 pa = *(const bf16x8*)&Ps[wave][mi * 16 + lr][kk * 32 + (lg << 3)];
      #pragma unroll
      for (int nj = 0; nj < 2; ++nj)
        o[mi][nj] = __builtin_amdgcn_mfma_f32_16x16x32_bf16(pa, vf[nj], o[mi][nj], 0, 0, 0);
    }
  }
  // attnout[b][win][t][h*32+d] (k-contiguous rows for the out-proj GEMM)
  bf16* dst = ao + ((size_t)(b * 64 + win) * 64) * 512 + h * 32;
  #pragma unroll
  for (int mi = 0; mi < 4; ++mi)
    #pragma unroll
    for (int r = 0; r < 4; ++r) {
      int t = mi * 16 + (lg << 2) + r;
      #pragma unroll
      for (int nj = 0; nj < 2; ++nj)
        dst[(size_t)t * 512 + nj * 16 + lr] = (bf16)o[mi][nj][r];
    }
}

// ---------------- out-proj GEMM + bias + inverse roll ----------------
__global__ __launch_bounds__(256, 2) void gemm_out(
    const bf16* __restrict__ ao, const bf16* __restrict__ wob,
    const float* __restrict__ bout, float* __restrict__ out) {
  __shared__ struct { bf16 A[128][32]; bf16 B[128][32]; } sm;
  const int tid = threadIdx.x, wave = tid >> 6, lane = tid & 63;
  const int bid = blockIdx.x;
  const int mt = bid >> 2, nt = bid & 3;
  const bf16* Ag = ao + ((size_t)mt * 128) * 512;
  const bf16* Bg = wob + ((size_t)nt * 128) * 512;
  const int srow = (wave << 5) + (lane >> 2);
  const int scol = (lane & 3) << 3;
  const bf16* ga = Ag + (size_t)srow * 512 + scol;
  const bf16* gb = Bg + (size_t)srow * 512 + scol;
  bf16* ldsA = &sm.A[wave << 5][0];
  bf16* ldsB = &sm.B[wave << 5][0];
  const int wr = (wave >> 1) << 6, wc = (wave & 1) << 6;
  const int lr = lane & 15, lg = lane >> 4;
  f32x4 acc[4][4] = {};
  for (int kt = 0; kt < 16; ++kt) {
    __syncthreads();
    gload_lds16(ga + kt * 32, ldsA);
    gload_lds16(ga + kt * 32 + 16 * 512, ldsA + 512);
    gload_lds16(gb + kt * 32, ldsB);
    gload_lds16(gb + kt * 32 + 16 * 512, ldsB + 512);
    __syncthreads();
    bf16x8 af[4], bfr[4];
    #pragma unroll
    for (int i = 0; i < 4; ++i) {
      af[i]  = *(const bf16x8*)&sm.A[wr + i * 16 + lr][lg << 3];
      bfr[i] = *(const bf16x8*)&sm.B[wc + i * 16 + lr][lg << 3];
    }
    #pragma unroll
    for (int i = 0; i < 4; ++i)
      #pragma unroll
      for (int j = 0; j < 4; ++j)
        acc[i][j] = __builtin_amdgcn_mfma_f32_16x16x32_bf16(af[i], bfr[j], acc[i][j], 0, 0, 0);
  }
  float bv[4];
  #pragma unroll
  for (int j = 0; j < 4; ++j) bv[j] = bout[nt * 128 + wc + j * 16 + lr];
  #pragma unroll
  for (int i = 0; i < 4; ++i)
    #pragma unroll
    for (int r = 0; r < 4; ++r) {
      int m = (mt << 7) + wr + i * 16 + (lg << 2) + r;
      int b = m >> 12, win = (m >> 6) & 63, t = m & 63;
      int ip = ((win >> 3) << 3) + (t >> 3);
      int jp = ((win & 7) << 3) + (t & 7);
      int io = (ip + 4) & 63, jo = (jp + 4) & 63;
      float* orow = out + ((((size_t)(b << 6) + io) << 6) + jo) * 512 + nt * 128 + wc;
      #pragma unroll
      for (int j = 0; j < 4; ++j)
        orow[j * 16 + lr] = acc[i][j][r] + bv[j];
    }
}

extern "C" void kernel_launch(void* const* d_in, const int* in_sizes, int n_in,
                              void* d_out, int out_size, void* d_ws, size_t ws_size,
                              hipStream_t stream) {
  const float* x    = (const float*)d_in[0];
  const float* wqkv = (const float*)d_in[1];
  const float* pos  = (const float*)d_in[2];
  const float* wout = (const float*)d_in[3];
  const float* bout = (const float*)d_in[4];
  float* out = (float*)d_out;

  char* ws = (char*)d_ws;
  bf16* xs      = (bf16*)(ws);                    // 67108864 B; later reused as attn out
  bf16* qb      = (bf16*)(ws + 67108864);
  bf16* kb      = (bf16*)(ws + 134217728);
  bf16* vb      = (bf16*)(ws + 201326592);
  bf16* wqkv_bf = (bf16*)(ws + 268435456);
  bf16* wout_bf = (bf16*)(ws + 270008320);
  float* bias4  = (float*)(ws + 270532608);       // total 270598144 B

  prep_x<<<dim3(8192), dim3(256), 0, stream>>>(x, xs);
  prep_w<<<dim3(256), dim3(256), 0, stream>>>(wqkv, wout, wqkv_bf, wout_bf);
  prep_bias<<<dim3(1), dim3(256), 0, stream>>>(pos, bias4);
  gemm_qkv<<<dim3(6144), dim3(256), 0, stream>>>(xs, wqkv_bf, qb, kb, vb);
  attn<<<dim3(4096), dim3(256), 0, stream>>>(qb, kb, vb, bias4, xs);
  gemm_out<<<dim3(2048), dim3(256), 0, stream>>>(xs, wout_bf, bout, out);
}

// Round 2
// 317.000 us; speedup vs baseline: 1.0295x; 1.0295x over previous
//
#include <hip/hip_runtime.h>
#include <hip/hip_bf16.h>
#include <stdint.h>

typedef __bf16 bf16;
typedef __attribute__((ext_vector_type(4))) float f32x4;
typedef __attribute__((ext_vector_type(8))) bf16 bf16x8;
typedef __attribute__((ext_vector_type(4))) bf16 bf16x4;

#define AS1 __attribute__((address_space(1)))
#define AS3 __attribute__((address_space(3)))

static __device__ __forceinline__ void gload_lds16(const bf16* g, bf16* l) {
  __builtin_amdgcn_global_load_lds((const AS1 void*)g, (AS3 void*)l, 16, 0, 0);
}

// ---------------- prep: roll + reorder + fp32->bf16 ----------------
__global__ __launch_bounds__(256) void prep_x(const float* __restrict__ x,
                                              bf16* __restrict__ xs) {
  int m = blockIdx.x * 8 + (threadIdx.x >> 5);
  int lane = threadIdx.x & 31;
  int b = m >> 12, win = (m >> 6) & 63, t = m & 63;
  int ip = ((win >> 3) << 3) + (t >> 3);
  int jp = ((win & 7) << 3) + (t & 7);
  int io = (ip + 4) & 63, jo = (jp + 4) & 63;
  const float* src = x + ((((size_t)(b << 6) + io) << 6) + jo) * 512;
  bf16* dst = xs + ((size_t)m << 9);
  #pragma unroll
  for (int c0 = 0; c0 < 512; c0 += 128) {
    int c = c0 + lane * 4;
    float4 v = *(const float4*)(src + c);
    bf16x4 o = { (bf16)v.x, (bf16)v.y, (bf16)v.z, (bf16)v.w };
    *(bf16x4*)(dst + c) = o;
  }
}

__global__ __launch_bounds__(256) void prep_w(const float* __restrict__ wqkv,
                                              const float* __restrict__ wout,
                                              bf16* __restrict__ wqkv_bf,
                                              bf16* __restrict__ wout_bf) {
  int r = blockIdx.x * 8 + (threadIdx.x >> 5);
  int lane = threadIdx.x & 31;
  const float* src;
  bf16* dst;
  float sc = 1.0f;
  if (r < 1536) {
    src = wqkv + (size_t)r * 512;
    dst = wqkv_bf + (size_t)r * 512;
    if (r < 512) sc = 0.17677669529663689f;
  } else {
    int r2 = r - 1536;
    src = wout + (size_t)r2 * 512;
    dst = wout_bf + (size_t)r2 * 512;
  }
  #pragma unroll
  for (int c0 = 0; c0 < 512; c0 += 128) {
    int c = c0 + lane * 4;
    float4 v = *(const float4*)(src + c);
    bf16x4 o = { (bf16)(v.x * sc), (bf16)(v.y * sc), (bf16)(v.z * sc), (bf16)(v.w * sc) };
    *(bf16x4*)(dst + c) = o;
  }
}

__global__ __launch_bounds__(256) void prep_bias(const float* __restrict__ pos,
                                                 float* __restrict__ bias4) {
  for (int idx = threadIdx.x; idx < 4 * 4096; idx += 256) {
    int ty = idx >> 12, ij = idx & 4095;
    int i = ij >> 6, j = ij & 63;
    int rx = ((j >> 3) - (i >> 3)) + 7;
    int ry = ((j & 7) - (i & 7)) + 7;
    float v = pos[rx * 15 + ry];
    if ((ty & 1) && (((i ^ j) >> 5) & 1)) v = -1e30f;
    if ((ty & 2) && (((i ^ j) >> 2) & 1)) v = -1e30f;
    bias4[idx] = v;
  }
}

// ---------------- QKV GEMM: [65536,512] x [1536,512]^T ----------------
// 128x128 tile, BK=32, 2-phase pipeline (prefetch next K-tile before compute),
// chunk-swizzled LDS (pre-swizzled global source), XCD-aware block swizzle.
__global__ __launch_bounds__(256, 2) void gemm_qkv(
    const bf16* __restrict__ xs, const bf16* __restrict__ wb,
    bf16* __restrict__ qb, bf16* __restrict__ kb, bf16* __restrict__ vb) {
  __shared__ union {
    struct { bf16 A[128][32]; bf16 B[128][32]; } buf[2];
    bf16 C[128][128];
  } sm;
  const int tid = threadIdx.x, wave = tid >> 6, lane = tid & 63;
  int bid = blockIdx.x;
  bid = (bid & 7) * 768 + (bid >> 3);          // XCD swizzle (6144 = 8*768)
  const int mt = bid / 12, nt = bid % 12;

  const bf16* Ag = xs + ((size_t)mt * 128) * 512;
  const bf16* Bg = wb + ((size_t)nt * 128) * 512;
  const int srow = (wave << 5) + (lane >> 2);
  const int schunk = (lane & 3) ^ ((srow >> 1) & 3);   // inverse-swizzled source
  const bf16* ga = Ag + (size_t)srow * 512 + (schunk << 3);
  const bf16* gb = Bg + (size_t)srow * 512 + (schunk << 3);
  const int ldso = (wave << 5) * 32;           // wave's row base (elements)

  const int wr = (wave >> 1) << 6, wc = (wave & 1) << 6;
  const int lr = lane & 15, lg = lane >> 4;

  f32x4 acc[4][4] = {};

  // prologue: stage kt=0 into buf 0
  {
    bf16* lA = &sm.buf[0].A[0][0] + ldso;
    bf16* lB = &sm.buf[0].B[0][0] + ldso;
    gload_lds16(ga, lA);
    gload_lds16(ga + 16 * 512, lA + 512);
    gload_lds16(gb, lB);
    gload_lds16(gb + 16 * 512, lB + 512);
  }
  __syncthreads();
  int cur = 0;
  for (int kt = 0; kt < 16; ++kt) {
    if (kt < 15) {
      bf16* lA = &sm.buf[cur ^ 1].A[0][0] + ldso;
      bf16* lB = &sm.buf[cur ^ 1].B[0][0] + ldso;
      const bf16* gA = ga + (kt + 1) * 32;
      const bf16* gB = gb + (kt + 1) * 32;
      gload_lds16(gA, lA);
      gload_lds16(gA + 16 * 512, lA + 512);
      gload_lds16(gB, lB);
      gload_lds16(gB + 16 * 512, lB + 512);
    }
    bf16x8 af[4], bfr[4];
    #pragma unroll
    for (int i = 0; i < 4; ++i) {
      int ra = wr + i * 16 + lr;
      int rb = wc + i * 16 + lr;
      af[i]  = *(const bf16x8*)&sm.buf[cur].A[ra][(lg ^ ((ra >> 1) & 3)) << 3];
      bfr[i] = *(const bf16x8*)&sm.buf[cur].B[rb][(lg ^ ((rb >> 1) & 3)) << 3];
    }
    #pragma unroll
    for (int i = 0; i < 4; ++i)
      #pragma unroll
      for (int j = 0; j < 4; ++j)
        acc[i][j] = __builtin_amdgcn_mfma_f32_16x16x32_bf16(af[i], bfr[j], acc[i][j], 0, 0, 0);
    __syncthreads();
    cur ^= 1;
  }
  // acc -> swizzled bf16 C tile in LDS
  #pragma unroll
  for (int i = 0; i < 4; ++i)
    #pragma unroll
    for (int j = 0; j < 4; ++j)
      #pragma unroll
      for (int r = 0; r < 4; ++r) {
        int row = wr + i * 16 + (lg << 2) + r;
        int col = wc + j * 16 + lr;
        sm.C[row][col ^ ((row & 7) << 3)] = (bf16)acc[i][j][r];
      }
  __syncthreads();
  const int sel = nt >> 2;
  #pragma unroll
  for (int ch = 0; ch < 2; ++ch) {
    int c = wave * 2 + ch;
    int wl = c >> 2, hl = c & 3;
    int gw = mt * 2 + wl;
    int b = gw >> 6, win = gw & 63;
    int h = ((nt & 3) << 2) + hl;
    size_t ubase = ((size_t)((b << 4) + h) * 64 + win) * 2048;
    if (sel < 2) {
      bf16* dst = (sel == 0 ? qb : kb) + ubase;
      #pragma unroll
      for (int p = 0; p < 4; ++p) {
        int off = p * 512 + lane * 8;
        int t = off >> 5, d = off & 31;
        int row = (wl << 6) + t, col = (hl << 5) + d;
        bf16x8 v = *(const bf16x8*)&sm.C[row][col ^ ((row & 7) << 3)];
        *(bf16x8*)(dst + off) = v;
      }
    } else {
      bf16* dst = vb + ubase;
      #pragma unroll
      for (int p = 0; p < 4; ++p) {
        int off = p * 512 + lane * 8;
        int d = off >> 6, t0 = off & 63;
        int col = (hl << 5) + d;
        bf16x8 v;
        #pragma unroll
        for (int q = 0; q < 8; ++q) {
          int row = (wl << 6) + t0 + q;
          v[q] = sm.C[row][col ^ ((row & 7) << 3)];
        }
        *(bf16x8*)(dst + off) = v;
      }
    }
  }
}

// ---------------- window attention: 1 wave per (b,h,win) ----------------
__global__ __launch_bounds__(256) void attn(
    const bf16* __restrict__ qb, const bf16* __restrict__ kb,
    const bf16* __restrict__ vb, const float* __restrict__ bias4,
    bf16* __restrict__ ao) {
  __shared__ bf16 Ps[4][64][72];
  const int wave = threadIdx.x >> 6, lane = threadIdx.x & 63;
  const int u = blockIdx.x * 4 + wave;
  const int b = u >> 10, h = (u >> 6) & 15, win = u & 63;
  const int lr = lane & 15, lg = lane >> 4;

  const bf16* qu = qb + (size_t)u * 2048;
  const bf16* ku = kb + (size_t)u * 2048;
  const bf16* vu = vb + (size_t)u * 2048;

  bf16x8 qf[4], kf[4];
  #pragma unroll
  for (int i = 0; i < 4; ++i) {
    qf[i] = *(const bf16x8*)(qu + (i * 16 + lr) * 32 + (lg << 3));
    kf[i] = *(const bf16x8*)(ku + (i * 16 + lr) * 32 + (lg << 3));
  }
  f32x4 s[4][4] = {};
  #pragma unroll
  for (int i = 0; i < 4; ++i)
    #pragma unroll
    for (int j = 0; j < 4; ++j)
      s[i][j] = __builtin_amdgcn_mfma_f32_16x16x32_bf16(qf[i], kf[j], s[i][j], 0, 0, 0);

  const int ty = ((win >= 56) ? 1 : 0) | (((win & 7) == 7) ? 2 : 0);
  const float* bt = bias4 + ty * 4096;
  #pragma unroll
  for (int i = 0; i < 4; ++i)
    #pragma unroll
    for (int r = 0; r < 4; ++r) {
      int row = i * 16 + (lg << 2) + r;
      #pragma unroll
      for (int j = 0; j < 4; ++j)
        s[i][j][r] += bt[row * 64 + j * 16 + lr];
    }
  #pragma unroll
  for (int i = 0; i < 4; ++i)
    #pragma unroll
    for (int r = 0; r < 4; ++r) {
      float mx = fmaxf(fmaxf(s[i][0][r], s[i][1][r]), fmaxf(s[i][2][r], s[i][3][r]));
      mx = fmaxf(mx, __shfl_xor(mx, 1));
      mx = fmaxf(mx, __shfl_xor(mx, 2));
      mx = fmaxf(mx, __shfl_xor(mx, 4));
      mx = fmaxf(mx, __shfl_xor(mx, 8));
      float sum = 0.f;
      #pragma unroll
      for (int j = 0; j < 4; ++j) { s[i][j][r] = __expf(s[i][j][r] - mx); sum += s[i][j][r]; }
      sum += __shfl_xor(sum, 1);
      sum += __shfl_xor(sum, 2);
      sum += __shfl_xor(sum, 4);
      sum += __shfl_xor(sum, 8);
      float inv = 1.0f / sum;
      int row = i * 16 + (lg << 2) + r;
      #pragma unroll
      for (int j = 0; j < 4; ++j)
        Ps[wave][row][j * 16 + lr] = (bf16)(s[i][j][r] * inv);
    }
  f32x4 o[4][2] = {};
  #pragma unroll
  for (int kk = 0; kk < 2; ++kk) {
    bf16x8 vf[2];
    #pragma unroll
    for (int nj = 0; nj < 2; ++nj)
      vf[nj] = *(const bf16x8*)(vu + (nj * 16 + lr) * 64 + kk * 32 + (lg << 3));
    #pragma unroll
    for (int mi = 0; mi < 4; ++mi) {
      bf16x8 pa = *(const bf16x8*)&Ps[wave][mi * 16 + lr][kk * 32 + (lg << 3)];
      #pragma unroll
      for (int nj = 0; nj < 2; ++nj)
        o[mi][nj] = __builtin_amdgcn_mfma_f32_16x16x32_bf16(pa, vf[nj], o[mi][nj], 0, 0, 0);
    }
  }
  bf16* dst = ao + ((size_t)(b * 64 + win) * 64) * 512 + h * 32;
  #pragma unroll
  for (int mi = 0; mi < 4; ++mi)
    #pragma unroll
    for (int r = 0; r < 4; ++r) {
      int t = mi * 16 + (lg << 2) + r;
      #pragma unroll
      for (int nj = 0; nj < 2; ++nj)
        dst[(size_t)t * 512 + nj * 16 + lr] = (bf16)o[mi][nj][r];
    }
}

// ---------------- out-proj GEMM + bias + inverse roll ----------------
__global__ __launch_bounds__(256, 2) void gemm_out(
    const bf16* __restrict__ ao, const bf16* __restrict__ wob,
    const float* __restrict__ bout, float* __restrict__ out) {
  __shared__ struct { bf16 A[128][32]; bf16 B[128][32]; } sm[2];
  const int tid = threadIdx.x, wave = tid >> 6, lane = tid & 63;
  int bid = blockIdx.x;
  bid = (bid & 7) * 256 + (bid >> 3);          // XCD swizzle (2048 = 8*256)
  const int mt = bid >> 2, nt = bid & 3;
  const bf16* Ag = ao + ((size_t)mt * 128) * 512;
  const bf16* Bg = wob + ((size_t)nt * 128) * 512;
  const int srow = (wave << 5) + (lane >> 2);
  const int schunk = (lane & 3) ^ ((srow >> 1) & 3);
  const bf16* ga = Ag + (size_t)srow * 512 + (schunk << 3);
  const bf16* gb = Bg + (size_t)srow * 512 + (schunk << 3);
  const int ldso = (wave << 5) * 32;
  const int wr = (wave >> 1) << 6, wc = (wave & 1) << 6;
  const int lr = lane & 15, lg = lane >> 4;
  f32x4 acc[4][4] = {};
  {
    bf16* lA = &sm[0].A[0][0] + ldso;
    bf16* lB = &sm[0].B[0][0] + ldso;
    gload_lds16(ga, lA);
    gload_lds16(ga + 16 * 512, lA + 512);
    gload_lds16(gb, lB);
    gload_lds16(gb + 16 * 512, lB + 512);
  }
  __syncthreads();
  int cur = 0;
  for (int kt = 0; kt < 16; ++kt) {
    if (kt < 15) {
      bf16* lA = &sm[cur ^ 1].A[0][0] + ldso;
      bf16* lB = &sm[cur ^ 1].B[0][0] + ldso;
      const bf16* gA = ga + (kt + 1) * 32;
      const bf16* gB = gb + (kt + 1) * 32;
      gload_lds16(gA, lA);
      gload_lds16(gA + 16 * 512, lA + 512);
      gload_lds16(gB, lB);
      gload_lds16(gB + 16 * 512, lB + 512);
    }
    bf16x8 af[4], bfr[4];
    #pragma unroll
    for (int i = 0; i < 4; ++i) {
      int ra = wr + i * 16 + lr;
      int rb = wc + i * 16 + lr;
      af[i]  = *(const bf16x8*)&sm[cur].A[ra][(lg ^ ((ra >> 1) & 3)) << 3];
      bfr[i] = *(const bf16x8*)&sm[cur].B[rb][(lg ^ ((rb >> 1) & 3)) << 3];
    }
    #pragma unroll
    for (int i = 0; i < 4; ++i)
      #pragma unroll
      for (int j = 0; j < 4; ++j)
        acc[i][j] = __builtin_amdgcn_mfma_f32_16x16x32_bf16(af[i], bfr[j], acc[i][j], 0, 0, 0);
    __syncthreads();
    cur ^= 1;
  }
  float bv[4];
  #pragma unroll
  for (int j = 0; j < 4; ++j) bv[j] = bout[nt * 128 + wc + j * 16 + lr];
  #pragma unroll
  for (int i = 0; i < 4; ++i)
    #pragma unroll
    for (int r = 0; r < 4; ++r) {
      int m = (mt << 7) + wr + i * 16 + (lg << 2) + r;
      int b = m >> 12, win = (m >> 6) & 63, t = m & 63;
      int ip = ((win >> 3) << 3) + (t >> 3);
      int jp = ((win & 7) << 3) + (t & 7);
      int io = (ip + 4) & 63, jo = (jp + 4) & 63;
      float* orow = out + ((((size_t)(b << 6) + io) << 6) + jo) * 512 + nt * 128 + wc;
      #pragma unroll
      for (int j = 0; j < 4; ++j)
        orow[j * 16 + lr] = acc[i][j][r] + bv[j];
    }
}

extern "C" void kernel_launch(void* const* d_in, const int* in_sizes, int n_in,
                              void* d_out, int out_size, void* d_ws, size_t ws_size,
                              hipStream_t stream) {
  const float* x    = (const float*)d_in[0];
  const float* wqkv = (const float*)d_in[1];
  const float* pos  = (const float*)d_in[2];
  const float* wout = (const float*)d_in[3];
  const float* bout = (const float*)d_in[4];
  float* out = (float*)d_out;

  char* ws = (char*)d_ws;
  bf16* xs      = (bf16*)(ws);
  bf16* qb      = (bf16*)(ws + 67108864);
  bf16* kb      = (bf16*)(ws + 134217728);
  bf16* vb      = (bf16*)(ws + 201326592);
  bf16* wqkv_bf = (bf16*)(ws + 268435456);
  bf16* wout_bf = (bf16*)(ws + 270008320);
  float* bias4  = (float*)(ws + 270532608);

  prep_x<<<dim3(8192), dim3(256), 0, stream>>>(x, xs);
  prep_w<<<dim3(256), dim3(256), 0, stream>>>(wqkv, wout, wqkv_bf, wout_bf);
  prep_bias<<<dim3(1), dim3(256), 0, stream>>>(pos, bias4);
  gemm_qkv<<<dim3(6144), dim3(256), 0, stream>>>(xs, wqkv_bf, qb, kb, vb);
  attn<<<dim3(4096), dim3(256), 0, stream>>>(qb, kb, vb, bias4, xs);
  gemm_out<<<dim3(2048), dim3(256), 0, stream>>>(xs, wout_bf, bout, out);
}

// Round 4
// 304.374 us; speedup vs baseline: 1.0722x; 1.0415x over previous
//
#include <hip/hip_runtime.h>
#include <hip/hip_bf16.h>
#include <stdint.h>

typedef __bf16 bf16;
typedef __attribute__((ext_vector_type(4))) float f32x4;
typedef __attribute__((ext_vector_type(8))) bf16 bf16x8;
typedef __attribute__((ext_vector_type(4))) bf16 bf16x4;

#define AS1 __attribute__((address_space(1)))
#define AS3 __attribute__((address_space(3)))

static __device__ __forceinline__ void gload_lds16(const bf16* g, bf16* l) {
  __builtin_amdgcn_global_load_lds((const AS1 void*)g, (AS3 void*)l, 16, 0, 0);
}

#define BAR __builtin_amdgcn_s_barrier()
#define LGKM0 asm volatile("s_waitcnt lgkmcnt(0)" ::: "memory")
#define VMC(n) asm volatile("s_waitcnt vmcnt(" #n ")" ::: "memory")

// Stage one 128x64 half-tile (16 KB): 512 threads x 2 gload_lds16.
// LDS dest linear; global source chunk-XOR pre-swizzled (chunk ^= row&7).
#define STAGE(gbase, slotbase, h, kt_) do {                                   \
  int r_ = tid >> 3, c_ = tid & 7;                                            \
  int cs_ = ((c_ ^ (r_ & 7)) << 3);                                           \
  const bf16* s0_ = (gbase) + (((size_t)((h) * 128 + r_)) << 9) + ((kt_) << 6) + cs_; \
  bf16* d0_ = (slotbase) + (h) * 8192 + tid * 8;                              \
  gload_lds16(s0_, d0_);                                                      \
  gload_lds16(s0_ + (size_t)(64 << 9), d0_ + 4096);                           \
} while (0)

// A-frags: 4 rowblocks x 2 ksteps from wave's A-half (wm), sub=0/1 (rows 0-63/64-127)
#define RD_A(dst, sbase, sub) do {                                            \
  const bf16* ab_ = (sbase) + wm * 8192;                                      \
  _Pragma("unroll") for (int rb_ = 0; rb_ < 4; ++rb_) {                       \
    int r_ = (sub) * 64 + rb_ * 16 + lr;                                      \
    _Pragma("unroll") for (int ks_ = 0; ks_ < 2; ++ks_)                       \
      dst[rb_][ks_] = *(const bf16x8*)(ab_ + r_ * 64 + (((ks_ * 4 + lg) ^ (r_ & 7)) << 3)); \
  }                                                                           \
} while (0)

// B-frags: 2 colblocks x 2 ksteps from wave's B-half strip
#define RD_B(dst, sbase, cb0) do {                                            \
  const bf16* bb_ = (sbase) + hb * 8192 + ((wn & 1) << 12);                   \
  _Pragma("unroll") for (int cb_ = 0; cb_ < 2; ++cb_) {                       \
    int rr_ = ((cb0) + cb_) * 16 + lr;                                        \
    _Pragma("unroll") for (int ks_ = 0; ks_ < 2; ++ks_)                       \
      dst[cb_][ks_] = *(const bf16x8*)(bb_ + rr_ * 64 + (((ks_ * 4 + lg) ^ (rr_ & 7)) << 3)); \
  }                                                                           \
} while (0)

#define MM(asub, bsub, r0, c0)                                                \
  _Pragma("unroll") for (int i_ = 0; i_ < 4; ++i_)                            \
  _Pragma("unroll") for (int j_ = 0; j_ < 2; ++j_)                            \
  _Pragma("unroll") for (int ks_ = 0; ks_ < 2; ++ks_)                         \
    acc[(r0) + i_][(c0) + j_] = __builtin_amdgcn_mfma_f32_16x16x32_bf16(      \
        asub[i_][ks_], bsub[j_][ks_], acc[(r0) + i_][(c0) + j_], 0, 0, 0);

// 8-phase K-loop (BM=BN=256, BK=64, 8 K-tiles). Cross-wave rule: every VMC
// that publishes staged data sits BEFORE the closing barrier of the phase
// preceding the first ds_read of that data (vmcnt is per-wave; only
// VMC->BAR->read is a valid publish).
#define KLOOP_256(Ag, Bg)                                                     \
  f32x4 acc[8][4] = {};                                                       \
  bf16x8 a_lo[4][2], a_hi[4][2], b_lo[2][2], b_hi[2][2];                      \
  STAGE(Bg, SB0, 0, 0); STAGE(Bg, SB0, 1, 0);                                 \
  STAGE(Ag, SA0, 0, 0); STAGE(Ag, SA0, 1, 0);                                 \
  STAGE(Ag, SA1, 0, 1); STAGE(Ag, SA1, 1, 1);                                 \
  VMC(4); BAR;                                                                \
  RD_A(a_lo, SA0, 0);                                                         \
  _Pragma("unroll 2")                                                         \
  for (int kt = 0; kt < 8; ++kt) {                                            \
    bf16* SAp = (kt & 1) ? SA1 : SA0;                                         \
    bf16* SAn = (kt & 1) ? SA0 : SA1;                                         \
    bf16* SBp = (kt & 1) ? SB1 : SB0;                                         \
    bf16* SBn = (kt & 1) ? SB0 : SB1;                                         \
    /* ph0: B(kt) published at kt-1 ph3 (VMC->BAR) */                         \
    RD_B(b_lo, SBp, 0); RD_B(b_hi, SBp, 2);                                   \
    if (kt < 7) STAGE(Bg, SBn, 0, kt + 1);                                    \
    BAR; LGKM0;                                                               \
    __builtin_amdgcn_s_setprio(1); MM(a_lo, b_lo, 0, 0);                      \
    __builtin_amdgcn_s_setprio(0); BAR;                                       \
    /* ph1 */                                                                 \
    RD_A(a_hi, SAp, 1);                                                       \
    if (kt < 7) STAGE(Bg, SBn, 1, kt + 1);                                    \
    BAR; LGKM0;                                                               \
    __builtin_amdgcn_s_setprio(1); MM(a_lo, b_hi, 0, 2);                      \
    __builtin_amdgcn_s_setprio(0); BAR;                                       \
    /* ph2: publish A(kt+1) for ph3's RD_A */                                 \
    if (kt < 6) STAGE(Ag, SAp, 0, kt + 2);                                    \
    if (kt < 7) { if (kt < 6) { VMC(6); } else { VMC(4); } }                  \
    BAR;                                                                      \
    __builtin_amdgcn_s_setprio(1); MM(a_hi, b_lo, 4, 0);                      \
    __builtin_amdgcn_s_setprio(0); BAR;                                       \
    /* ph3: publish B(kt+1) for next ph0's RD_B */                            \
    if (kt < 7) RD_A(a_lo, SAn, 0);                                           \
    if (kt < 6) STAGE(Ag, SAp, 1, kt + 2);                                    \
    if (kt < 7) { if (kt < 6) { VMC(4); } else { VMC(0); } }                  \
    BAR; LGKM0;                                                               \
    __builtin_amdgcn_s_setprio(1); MM(a_hi, b_hi, 4, 2);                      \
    __builtin_amdgcn_s_setprio(0); BAR;                                       \
  }

// ---------------- prep: roll + reorder + fp32->bf16 ----------------
__global__ __launch_bounds__(256) void prep_x(const float* __restrict__ x,
                                              bf16* __restrict__ xs) {
  int m = blockIdx.x * 8 + (threadIdx.x >> 5);
  int lane = threadIdx.x & 31;
  int b = m >> 12, win = (m >> 6) & 63, t = m & 63;
  int ip = ((win >> 3) << 3) + (t >> 3);
  int jp = ((win & 7) << 3) + (t & 7);
  int io = (ip + 4) & 63, jo = (jp + 4) & 63;
  const float* src = x + ((((size_t)(b << 6) + io) << 6) + jo) * 512;
  bf16* dst = xs + ((size_t)m << 9);
  #pragma unroll
  for (int c0 = 0; c0 < 512; c0 += 128) {
    int c = c0 + lane * 4;
    float4 v = *(const float4*)(src + c);
    bf16x4 o = { (bf16)v.x, (bf16)v.y, (bf16)v.z, (bf16)v.w };
    *(bf16x4*)(dst + c) = o;
  }
}

__global__ __launch_bounds__(256) void prep_w(const float* __restrict__ wqkv,
                                              const float* __restrict__ wout,
                                              bf16* __restrict__ wqkv_bf,
                                              bf16* __restrict__ wout_bf) {
  int r = blockIdx.x * 8 + (threadIdx.x >> 5);
  int lane = threadIdx.x & 31;
  const float* src;
  bf16* dst;
  float sc = 1.0f;
  if (r < 1536) {
    src = wqkv + (size_t)r * 512;
    dst = wqkv_bf + (size_t)r * 512;
    if (r < 512) sc = 0.17677669529663689f;
  } else {
    int r2 = r - 1536;
    src = wout + (size_t)r2 * 512;
    dst = wout_bf + (size_t)r2 * 512;
  }
  #pragma unroll
  for (int c0 = 0; c0 < 512; c0 += 128) {
    int c = c0 + lane * 4;
    float4 v = *(const float4*)(src + c);
    bf16x4 o = { (bf16)(v.x * sc), (bf16)(v.y * sc), (bf16)(v.z * sc), (bf16)(v.w * sc) };
    *(bf16x4*)(dst + c) = o;
  }
}

__global__ __launch_bounds__(256) void prep_bias(const float* __restrict__ pos,
                                                 float* __restrict__ bias4) {
  for (int idx = threadIdx.x; idx < 4 * 4096; idx += 256) {
    int ty = idx >> 12, ij = idx & 4095;
    int i = ij >> 6, j = ij & 63;
    int rx = ((j >> 3) - (i >> 3)) + 7;
    int ry = ((j & 7) - (i & 7)) + 7;
    float v = pos[rx * 15 + ry];
    if ((ty & 1) && (((i ^ j) >> 5) & 1)) v = -1e30f;
    if ((ty & 2) && (((i ^ j) >> 2) & 1)) v = -1e30f;
    bias4[idx] = v;
  }
}

// ---------------- QKV GEMM: 256x256 tile, 8-phase pipelined ----------------
__global__ __launch_bounds__(512, 1) void gemm_qkv(
    const bf16* __restrict__ xs, const bf16* __restrict__ wb,
    bf16* __restrict__ qb, bf16* __restrict__ kb, bf16* __restrict__ vb) {
  __shared__ union {
    struct { bf16 A[2][16384]; bf16 B[2][16384]; } s;
    bf16 C[256][256];
  } sm;
  bf16* SA0 = sm.s.A[0]; bf16* SA1 = sm.s.A[1];
  bf16* SB0 = sm.s.B[0]; bf16* SB1 = sm.s.B[1];

  const int tid = threadIdx.x, wave = tid >> 6, lane = tid & 63;
  const int wm = wave >> 2, wn = wave & 3, hb = wn >> 1;
  const int lr = lane & 15, lg = lane >> 4;

  int bid = blockIdx.x;
  bid = (bid & 7) * 192 + (bid >> 3);          // XCD swizzle (1536 = 8*192)
  const int mt = bid / 6, nt = bid % 6;

  const bf16* Ag = xs + (((size_t)mt) << 17);  // mt*256*512
  const bf16* Bg = wb + (((size_t)nt) << 17);

  KLOOP_256(Ag, Bg)

  __syncthreads();
  // acc -> swizzled bf16 C tile in LDS
  #pragma unroll
  for (int i = 0; i < 8; ++i)
    #pragma unroll
    for (int j = 0; j < 4; ++j)
      #pragma unroll
      for (int r = 0; r < 4; ++r) {
        int row = wm * 128 + i * 16 + (lg << 2) + r;
        int col = wn * 64 + j * 16 + lr;
        sm.C[row][col ^ ((row & 7) << 3)] = (bf16)acc[i][j][r];
      }
  __syncthreads();
  const int sel = nt >> 1;                     // 0=q, 1=k, 2=v
  #pragma unroll
  for (int ch = 0; ch < 4; ++ch) {
    int c = wave * 4 + ch;
    int wl = c >> 3, hl = c & 7;               // window-in-tile (0..3), head-in-tile (0..7)
    int gw = mt * 4 + wl;
    int b = gw >> 6, win = gw & 63;
    int h = ((nt & 1) << 3) + hl;
    size_t ubase = ((size_t)((b << 4) + h) * 64 + win) * 2048;
    if (sel < 2) {
      bf16* dst = (sel == 0 ? qb : kb) + ubase;
      #pragma unroll
      for (int p = 0; p < 4; ++p) {
        int off = p * 512 + lane * 8;
        int t = off >> 5, d = off & 31;
        int row = (wl << 6) + t, col = (hl << 5) + d;
        bf16x8 v = *(const bf16x8*)&sm.C[row][col ^ ((row & 7) << 3)];
        *(bf16x8*)(dst + off) = v;             // q/k: [t][d]
      }
    } else {
      bf16* dst = vb + ubase;
      #pragma unroll
      for (int p = 0; p < 4; ++p) {
        int off = p * 512 + lane * 8;
        int d = off >> 6, t0 = off & 63;
        int col = (hl << 5) + d;
        bf16x8 v;
        #pragma unroll
        for (int q = 0; q < 8; ++q) {
          int row = (wl << 6) + t0 + q;
          v[q] = sm.C[row][col ^ ((row & 7) << 3)];
        }
        *(bf16x8*)(dst + off) = v;             // v: [d][t] (transposed)
      }
    }
  }
}

// ---------------- window attention: 1 wave per (b,h,win) ----------------
__global__ __launch_bounds__(256) void attn(
    const bf16* __restrict__ qb, const bf16* __restrict__ kb,
    const bf16* __restrict__ vb, const float* __restrict__ bias4,
    bf16* __restrict__ ao) {
  __shared__ bf16 Ps[4][64][72];
  const int wave = threadIdx.x >> 6, lane = threadIdx.x & 63;
  const int u = blockIdx.x * 4 + wave;
  const int b = u >> 10, h = (u >> 6) & 15, win = u & 63;
  const int lr = lane & 15, lg = lane >> 4;

  const bf16* qu = qb + (size_t)u * 2048;
  const bf16* ku = kb + (size_t)u * 2048;
  const bf16* vu = vb + (size_t)u * 2048;

  bf16x8 qf[4], kf[4];
  #pragma unroll
  for (int i = 0; i < 4; ++i) {
    qf[i] = *(const bf16x8*)(qu + (i * 16 + lr) * 32 + (lg << 3));
    kf[i] = *(const bf16x8*)(ku + (i * 16 + lr) * 32 + (lg << 3));
  }
  f32x4 s[4][4] = {};
  #pragma unroll
  for (int i = 0; i < 4; ++i)
    #pragma unroll
    for (int j = 0; j < 4; ++j)
      s[i][j] = __builtin_amdgcn_mfma_f32_16x16x32_bf16(qf[i], kf[j], s[i][j], 0, 0, 0);

  const int ty = ((win >= 56) ? 1 : 0) | (((win & 7) == 7) ? 2 : 0);
  const float* bt = bias4 + ty * 4096;
  #pragma unroll
  for (int i = 0; i < 4; ++i)
    #pragma unroll
    for (int r = 0; r < 4; ++r) {
      int row = i * 16 + (lg << 2) + r;
      #pragma unroll
      for (int j = 0; j < 4; ++j)
        s[i][j][r] += bt[row * 64 + j * 16 + lr];
    }
  #pragma unroll
  for (int i = 0; i < 4; ++i)
    #pragma unroll
    for (int r = 0; r < 4; ++r) {
      float mx = fmaxf(fmaxf(s[i][0][r], s[i][1][r]), fmaxf(s[i][2][r], s[i][3][r]));
      mx = fmaxf(mx, __shfl_xor(mx, 1));
      mx = fmaxf(mx, __shfl_xor(mx, 2));
      mx = fmaxf(mx, __shfl_xor(mx, 4));
      mx = fmaxf(mx, __shfl_xor(mx, 8));
      float sum = 0.f;
      #pragma unroll
      for (int j = 0; j < 4; ++j) { s[i][j][r] = __expf(s[i][j][r] - mx); sum += s[i][j][r]; }
      sum += __shfl_xor(sum, 1);
      sum += __shfl_xor(sum, 2);
      sum += __shfl_xor(sum, 4);
      sum += __shfl_xor(sum, 8);
      float inv = 1.0f / sum;
      int row = i * 16 + (lg << 2) + r;
      #pragma unroll
      for (int j = 0; j < 4; ++j)
        Ps[wave][row][j * 16 + lr] = (bf16)(s[i][j][r] * inv);
    }
  f32x4 o[4][2] = {};
  #pragma unroll
  for (int kk = 0; kk < 2; ++kk) {
    bf16x8 vf[2];
    #pragma unroll
    for (int nj = 0; nj < 2; ++nj)
      vf[nj] = *(const bf16x8*)(vu + (nj * 16 + lr) * 64 + kk * 32 + (lg << 3));
    #pragma unroll
    for (int mi = 0; mi < 4; ++mi) {
      bf16x8 pa = *(const bf16x8*)&Ps[wave][mi * 16 + lr][kk * 32 + (lg << 3)];
      #pragma unroll
      for (int nj = 0; nj < 2; ++nj)
        o[mi][nj] = __builtin_amdgcn_mfma_f32_16x16x32_bf16(pa, vf[nj], o[mi][nj], 0, 0, 0);
    }
  }
  bf16* dst = ao + ((size_t)(b * 64 + win) * 64) * 512 + h * 32;
  #pragma unroll
  for (int mi = 0; mi < 4; ++mi)
    #pragma unroll
    for (int r = 0; r < 4; ++r) {
      int t = mi * 16 + (lg << 2) + r;
      #pragma unroll
      for (int nj = 0; nj < 2; ++nj)
        dst[(size_t)t * 512 + nj * 16 + lr] = (bf16)o[mi][nj][r];
    }
}

// ---------------- out-proj GEMM (256x256, 8-phase) + bias + inverse roll ----------------
__global__ __launch_bounds__(512, 1) void gemm_out(
    const bf16* __restrict__ ao, const bf16* __restrict__ wob,
    const float* __restrict__ bout, float* __restrict__ out) {
  __shared__ struct { bf16 A[2][16384]; bf16 B[2][16384]; } sm;
  bf16* SA0 = sm.A[0]; bf16* SA1 = sm.A[1];
  bf16* SB0 = sm.B[0]; bf16* SB1 = sm.B[1];

  const int tid = threadIdx.x, wave = tid >> 6, lane = tid & 63;
  const int wm = wave >> 2, wn = wave & 3, hb = wn >> 1;
  const int lr = lane & 15, lg = lane >> 4;

  int bid = blockIdx.x;
  bid = (bid & 7) * 64 + (bid >> 3);           // XCD swizzle (512 = 8*64)
  const int mt = bid >> 1, nt = bid & 1;

  const bf16* Ag = ao + (((size_t)mt) << 17);
  const bf16* Bg = wob + (((size_t)nt) << 17);

  KLOOP_256(Ag, Bg)

  float bv[4];
  #pragma unroll
  for (int j = 0; j < 4; ++j) bv[j] = bout[nt * 256 + wn * 64 + j * 16 + lr];
  #pragma unroll
  for (int i = 0; i < 8; ++i)
    #pragma unroll
    for (int r = 0; r < 4; ++r) {
      int m = mt * 256 + wm * 128 + i * 16 + (lg << 2) + r;
      int b = m >> 12, win = (m >> 6) & 63, t = m & 63;
      int ip = ((win >> 3) << 3) + (t >> 3);
      int jp = ((win & 7) << 3) + (t & 7);
      int io = (ip + 4) & 63, jo = (jp + 4) & 63;
      float* orow = out + ((((size_t)(b << 6) + io) << 6) + jo) * 512 + nt * 256 + wn * 64;
      #pragma unroll
      for (int j = 0; j < 4; ++j)
        orow[j * 16 + lr] = acc[i][j][r] + bv[j];
    }
}

extern "C" void kernel_launch(void* const* d_in, const int* in_sizes, int n_in,
                              void* d_out, int out_size, void* d_ws, size_t ws_size,
                              hipStream_t stream) {
  const float* x    = (const float*)d_in[0];
  const float* wqkv = (const float*)d_in[1];
  const float* pos  = (const float*)d_in[2];
  const float* wout = (const float*)d_in[3];
  const float* bout = (const float*)d_in[4];
  float* out = (float*)d_out;

  char* ws = (char*)d_ws;
  bf16* xs      = (bf16*)(ws);
  bf16* qb      = (bf16*)(ws + 67108864);
  bf16* kb      = (bf16*)(ws + 134217728);
  bf16* vb      = (bf16*)(ws + 201326592);
  bf16* wqkv_bf = (bf16*)(ws + 268435456);
  bf16* wout_bf = (bf16*)(ws + 270008320);
  float* bias4  = (float*)(ws + 270532608);

  prep_x<<<dim3(8192), dim3(256), 0, stream>>>(x, xs);
  prep_w<<<dim3(256), dim3(256), 0, stream>>>(wqkv, wout, wqkv_bf, wout_bf);
  prep_bias<<<dim3(1), dim3(256), 0, stream>>>(pos, bias4);
  gemm_qkv<<<dim3(1536), dim3(512), 0, stream>>>(xs, wqkv_bf, qb, kb, vb);
  attn<<<dim3(4096), dim3(256), 0, stream>>>(qb, kb, vb, bias4, xs);
  gemm_out<<<dim3(512), dim3(512), 0, stream>>>(xs, wout_bf, bout, out);
}